// Round 4
// baseline (184.172 us; speedup 1.0000x reference)
//
#include <hip/hip_runtime.h>
#include <math.h>

#define HW 2304           // 48*48
#define O192 192
#define SCALE_F 0.35355339059327373f   // 8^-0.5

typedef unsigned int u32;

// ---------------- Kernel A: 1x1 conv -> q,k (QKV) and v (V2) ----------------
__global__ __launch_bounds__(256) void qkv_kernel(
    const float* __restrict__ F, const float* __restrict__ W,
    float* __restrict__ QKV, float* __restrict__ V2) {
  __shared__ __align__(16) float sW[384];   // two o0 sets x {q,k,v} rows x 64
  int blk = blockIdx.x;
  int idx0 = blk * 256;
  int r0 = idx0 / HW;
  int r1 = (idx0 + 255) / HW;
  int tid = threadIdx.x;
  if (tid < 192) {
    int g = tid >> 6, c = tid & 63;
    sW[tid]       = W[((r0 & 63) + g * 64) * 64 + c];
    sW[192 + tid] = W[((r1 & 63) + g * 64) * 64 + c];
  }
  __syncthreads();
  int idx = idx0 + tid;
  int p  = idx % HW;
  int r  = idx / HW;
  int o0 = r & 63;
  int b  = r >> 6;
  const float4* w4 = (const float4*)(sW + ((r == r0) ? 0 : 192));
  const float* f = F + (b * 64) * HW + p;
  float aq = 0.f, ak = 0.f, av = 0.f;
  #pragma unroll 4
  for (int c4 = 0; c4 < 16; c4++) {
    float4 wq = w4[c4];
    float4 wk = w4[16 + c4];
    float4 wv = w4[32 + c4];
    float f0 = f[(c4 * 4 + 0) * HW];
    float f1 = f[(c4 * 4 + 1) * HW];
    float f2 = f[(c4 * 4 + 2) * HW];
    float f3 = f[(c4 * 4 + 3) * HW];
    aq = fmaf(wq.x, f0, aq); ak = fmaf(wk.x, f0, ak); av = fmaf(wv.x, f0, av);
    aq = fmaf(wq.y, f1, aq); ak = fmaf(wk.y, f1, ak); av = fmaf(wv.y, f1, av);
    aq = fmaf(wq.z, f2, aq); ak = fmaf(wk.z, f2, ak); av = fmaf(wv.z, f2, av);
    aq = fmaf(wq.w, f3, aq); ak = fmaf(wk.w, f3, ak); av = fmaf(wv.w, f3, av);
  }
  float* qp = QKV + (b * HW + p) * O192;
  qp[o0]      = aq;
  qp[o0 + 64] = ak;
  V2[(((b << 3) + (o0 >> 3)) * HW + p) * 8 + (o0 & 7)] = av;
}

// ---------------- Kernel B: 11x11 stride-8 conv + bias + exact GELU ----------
__global__ __launch_bounds__(256) void conv_kernel(
    const float* __restrict__ QKV, const float* __restrict__ Wq,
    const float* __restrict__ Bq, const float* __restrict__ Wk,
    const float* __restrict__ Bk, float* __restrict__ QD) {
  __shared__ float sW[7744];
  __shared__ float sRed[4 * 64 * 6];
  int blk = blockIdx.x;
  int xcd = blk & 7;
  int T = xcd >> 2, b = (xcd >> 1) & 1, s = xcd & 1;
  int idx = (blk >> 3) * 2 + s;
  int o  = idx / 6;
  int oy = idx % 6;
  const float* Wg = T ? Wk : Wq;
  for (int i = threadIdx.x; i < 7744; i += 256) sW[i] = Wg[o * 7744 + i];
  __syncthreads();
  int wv = threadIdx.x >> 6;
  int c  = threadIdx.x & 63;
  const float* base = QKV + b * (HW * O192) + T * 64 + c;
  float acc[6];
  #pragma unroll
  for (int ox = 0; ox < 6; ox++) acc[ox] = 0.f;
  for (int kyi = 0; kyi < 3; kyi++) {
    int ky = wv * 3 + kyi;
    if (ky > 10) break;
    int y = oy * 8 - 2 + ky;
    if ((unsigned)y < 48u) {
      float xrow[48];
      #pragma unroll
      for (int x = 0; x < 48; x++) xrow[x] = base[(y * 48 + x) * O192];
      #pragma unroll
      for (int kx = 0; kx < 11; kx++) {
        float wt = sW[c * 121 + ky * 11 + kx];
        #pragma unroll
        for (int ox = 0; ox < 6; ox++) {
          int x = ox * 8 - 2 + kx;
          if (x >= 0 && x < 48) acc[ox] = fmaf(xrow[x], wt, acc[ox]);
        }
      }
    }
  }
  #pragma unroll
  for (int ox = 0; ox < 6; ox++) sRed[(wv * 64 + c) * 6 + ox] = acc[ox];
  __syncthreads();
  if (threadIdx.x < 64) {
    int t = threadIdx.x;
    float r[6];
    #pragma unroll
    for (int ox = 0; ox < 6; ox++)
      r[ox] = sRed[t * 6 + ox] + sRed[(64 + t) * 6 + ox]
            + sRed[(128 + t) * 6 + ox] + sRed[(192 + t) * 6 + ox];
    #pragma unroll
    for (int off = 32; off; off >>= 1) {
      #pragma unroll
      for (int ox = 0; ox < 6; ox++) r[ox] += __shfl_down(r[ox], off, 64);
    }
    if (t == 0) {
      float bias = T ? Bk[o] : Bq[o];
      #pragma unroll
      for (int ox = 0; ox < 6; ox++) {
        float g = r[ox] + bias;
        float ge = 0.5f * g * (1.0f + erff(g * 0.70710678118654752f));
        QD[((T * 2 + b) * 64 + o) * 36 + oy * 6 + ox] = ge;
      }
    }
  }
}

// ---------------- Kernel C: full-j attention, v2 (round-3 redesign) ---------
// Lessons: no device fences (r1); no forced min-occupancy (r2); and NEW (r3):
//  * V staging in LDS was pointless -- main-loop V reads are wave-uniform
//    broadcasts, so read V2 straight from L2 (~83MB aggregate L2 traffic,
//    ~2.4us). Kills the DMA + per-quarter barrier structure (10 -> 2 barriers).
//  * 576 64-row blocks = 2.25/CU -> 33% VALU imbalance (3-vs-2 blocks/CU).
//    Regrain: 1152 blocks x 32 rows, 19.6KB LDS -> 4 blocks/CU (wave-bound),
//    streams with ~10% imbalance.
//  * sQ stored transposed [c][row] -> staging-phase LDS reads conflict-free
//    (was 16-way on stride-8).
// Block = (bh:16, S:72 of 32 rows). 512 thr = 8 waves; lane&31 = row rl,
// jx-group g = w*2 + (lane>>5) in [0,16), each group 3 jx. acc[9] per lane;
// pair-reduce via shfl_xor(32), then one LDS round across 8 waves.
#define OFF_EA  0        // 1536 f : eA [jy 0..47][rl 0..31]
#define OFF_PHT 1536     // 384  f : PH^T [jy][c]
#define OFF_PWT 1920     // 384  f : PW^T [jx][c]
#define OFF_E   2304     // 36+4 f : E [J]
#define OFF_QT  2344     // 256  f : sQT [c][row]  (transposed!)
#define OFF_R   2600     // 2304 f : sRed [8 waves][32 rows][9]
#define SBUF_N  4904     // 19616 B -> 4 blocks/CU (wave-slot bound)

__global__ __launch_bounds__(512, 4) void attn_kernel(
    const float* __restrict__ QKV, const float* __restrict__ V2,
    const float* __restrict__ QD, const float* __restrict__ PH,
    const float* __restrict__ PW, float* __restrict__ out) {
  __shared__ __align__(16) float sB[SBUF_N];
  int blk = blockIdx.x;
  int bh = blk / 72;
  int S  = blk - bh * 72;         // 32-row supertile; I column = S>>1
  int b = bh >> 3, h = bh & 7;
  int tid = threadIdx.x;
  int w = tid >> 6, lane = tid & 63;
  int rl = lane & 31;             // row within tile
  int g  = w * 2 + (lane >> 5);   // jx-group in [0,16), 3 jx each
  // ---- stage tables ----
  if (tid < 384) {
    sB[OFF_PHT + tid] = PH[(tid & 7) * 48 + (tid >> 3)];
    sB[OFF_PWT + tid] = PW[(tid & 7) * 48 + (tid >> 3)];
  }
  if (tid < 36) {   // fused dots: E[J] = exp(SCALE * qd[:,I].kd[:,J])
    int I = S >> 1;
    float acc = 0.f;
    #pragma unroll
    for (int c8 = 0; c8 < 8; c8++) {
      float qv = QD[((0 + b) * 64 + h * 8 + c8) * 36 + I];
      float kv = QD[((2 + b) * 64 + h * 8 + c8) * 36 + tid];
      acc = fmaf(qv, kv, acc);
    }
    sB[OFF_E + tid] = __expf(SCALE_F * acc);
  }
  if (tid < 256) {  // sQT[c][row] transposed: coalesced global, conflict-free LDS
    int row = tid >> 3, c = tid & 7;
    sB[OFF_QT + c * 32 + row] =
      QKV[(b * HW + S * 32 + row) * O192 + h * 8 + c];
  }
  __syncthreads();
  // ---- eA for ALL 48 jy: exp(q_row . PH[:,jy]) ----
  #pragma unroll
  for (int m = 0; m < 3; m++) {
    int flat = tid + m * 512;           // jy*32 + rl
    int jy = flat >> 5, r = flat & 31;
    const float* pp = sB + OFF_PHT + jy * 8;
    float d = 0.f;
    #pragma unroll
    for (int j = 0; j < 8; j++) d = fmaf(sB[OFF_QT + j * 32 + r], pp[j], d);
    sB[OFF_EA + flat] = __expf(d);
  }
  // ---- eB regs: this lane's 3 jx for its row ----
  float eB[3];
  #pragma unroll
  for (int i = 0; i < 3; i++) {
    const float* pp = sB + OFF_PWT + (g * 3 + i) * 8;
    float d = 0.f;
    #pragma unroll
    for (int j = 0; j < 8; j++) d = fmaf(sB[OFF_QT + j * 32 + rl], pp[j], d);
    eB[i] = __expf(d);
  }
  __syncthreads();
  // ---- main loop: 48 jy, V read straight from L2 (wave-uniform broadcast) --
  float acc[9];
  #pragma unroll
  for (int c = 0; c < 9; c++) acc[c] = 0.f;
  const float4* v4 = (const float4*)(V2 + (size_t)bh * (HW * 8));
  for (int jy = 0; jy < 48; jy++) {
    float eAk = sB[OFF_EA + jy * 32 + rl];
    int cb = jy * 48 + g * 3;                 // global j of i=0
    int J0 = cb >> 6, J1 = (cb + 2) >> 6;
    int ib = 64 - (cb & 63);                  // i >= ib uses J1
    float e0 = sB[OFF_E + J0];
    float e1 = sB[OFF_E + J1];
    float a0 = eAk * e0, a1 = eAk * e1;
    #pragma unroll
    for (int i = 0; i < 3; i++) {
      float4 vlo = v4[(cb + i) * 2];
      float4 vhi = v4[(cb + i) * 2 + 1];
      float wgt = (i < ib ? a0 : a1) * eB[i];
      acc[0] = fmaf(wgt, vlo.x, acc[0]);
      acc[1] = fmaf(wgt, vlo.y, acc[1]);
      acc[2] = fmaf(wgt, vlo.z, acc[2]);
      acc[3] = fmaf(wgt, vlo.w, acc[3]);
      acc[4] = fmaf(wgt, vhi.x, acc[4]);
      acc[5] = fmaf(wgt, vhi.y, acc[5]);
      acc[6] = fmaf(wgt, vhi.z, acc[6]);
      acc[7] = fmaf(wgt, vhi.w, acc[7]);
      acc[8] += wgt;
    }
  }
  // ---- reduce: pair (lane-halves) via shfl, then across 8 waves via LDS ----
  #pragma unroll
  for (int c = 0; c < 9; c++) acc[c] += __shfl_xor(acc[c], 32, 64);
  if (lane < 32) {
    #pragma unroll
    for (int c = 0; c < 9; c++) sB[OFF_R + (w * 32 + rl) * 9 + c] = acc[c];
  }
  __syncthreads();
  if (tid < 256) {
    int r = tid & 31, c = tid >> 5;   // c in 0..7
    float num = 0.f, z = 0.f;
    #pragma unroll
    for (int ww = 0; ww < 8; ww++) {
      num += sB[OFF_R + (ww * 32 + r) * 9 + c];
      z   += sB[OFF_R + (ww * 32 + r) * 9 + 8];
    }
    out[(b * 64 + h * 8 + c) * HW + S * 32 + r] = num / z;
  }
}

extern "C" void kernel_launch(void* const* d_in, const int* in_sizes, int n_in,
                              void* d_out, int out_size, void* d_ws, size_t ws_size,
                              hipStream_t stream) {
  const float* F    = (const float*)d_in[0];
  const float* Wqkv = (const float*)d_in[1];
  const float* Wq   = (const float*)d_in[2];
  const float* Bq   = (const float*)d_in[3];
  const float* Wk   = (const float*)d_in[4];
  const float* Bk   = (const float*)d_in[5];
  const float* PH   = (const float*)d_in[6];
  const float* PW   = (const float*)d_in[7];
  float* out = (float*)d_out;

  float* ws   = (float*)d_ws;
  float* QKV  = ws;                        // 884736 f
  float* V2   = QKV + 2 * HW * O192;       // 294912 f
  float* QD   = V2 + 2 * 8 * HW * 8;       // 9216 f   (~4.8 MB total)

  qkv_kernel <<<1152, 256, 0, stream>>>(F, Wqkv, QKV, V2);
  conv_kernel<<<1536, 256, 0, stream>>>(QKV, Wq, Bq, Wk, Bk, QD);
  attn_kernel<<<1152, 512, 0, stream>>>(QKV, V2, QD, PH, PW, out);
}